// Round 12
// baseline (331.339 us; speedup 1.0000x reference)
//
#include <hip/hip_runtime.h>
#include <hip/hip_bf16.h>

typedef __attribute__((ext_vector_type(8))) short bf16x8;
typedef __attribute__((ext_vector_type(4))) float f32x4;
typedef __attribute__((ext_vector_type(16))) float f32x16;
typedef __attribute__((ext_vector_type(2))) float f32x2;
typedef unsigned short u16;

#define Bc   2
#define Sc   2048
#define Dc   1024
#define Hc   16
#define HDc  64
#define ROTc 32
#define Mrows 4096  // B*S

__device__ __forceinline__ u16 f2bf(float x) {
  union { float f; unsigned u; } v{x};
  unsigned r = v.u + 0x7fffu + ((v.u >> 16) & 1u);
  return (u16)(r >> 16);
}
__device__ __forceinline__ float bf2f(u16 x) {
  union { unsigned u; float f; } v{(unsigned)x << 16};
  return v.f;
}
__device__ __forceinline__ unsigned cvtpk(float a, float b) {
  unsigned r;
  asm("v_cvt_pk_bf16_f32 %0, %1, %2" : "=v"(r) : "v"(a), "v"(b));
  return r;
}
__device__ __forceinline__ f32x2 pmax2(f32x2 a, f32x2 b) {
  f32x2 r;
  r.x = fmaxf(a.x, b.x);
  r.y = fmaxf(a.y, b.y);
  return r;
}

__device__ __forceinline__ void gload_lds16(const void* g, void* l) {
  __builtin_amdgcn_global_load_lds(
      (const __attribute__((address_space(1))) void*)g,
      (__attribute__((address_space(3))) void*)l, 16, 0, 0);
}

// ---------------- f32 -> bf16 conversion (hidden + 4 weights in one grid) --
__global__ void cvt_all(const float* __restrict__ h, const float* __restrict__ q,
                        const float* __restrict__ k, const float* __restrict__ v,
                        const float* __restrict__ o,
                        u16* __restrict__ hb, u16* __restrict__ qb, u16* __restrict__ kb,
                        u16* __restrict__ vb, u16* __restrict__ ob) {
  size_t i = ((size_t)blockIdx.x * 256 + threadIdx.x) * 4;
  const float* s;
  u16* d;
  size_t off;
  if (i < (size_t)Mrows * Dc) {
    s = h; d = hb; off = i;
  } else {
    size_t j = i - (size_t)Mrows * Dc;
    int w = (int)(j >> 20);            // 1M elements per weight
    off = j & ((1u << 20) - 1);
    s = (w == 0) ? q : (w == 1) ? k : (w == 2) ? v : o;
    d = (w == 0) ? qb : (w == 1) ? kb : (w == 2) ? vb : ob;
  }
  float4 val = *reinterpret_cast<const float4*>(s + off);
  u16 r0 = f2bf(val.x), r1 = f2bf(val.y), r2 = f2bf(val.z), r3 = f2bf(val.w);
  ushort4 outv = {r0, r1, r2, r3};
  *reinterpret_cast<ushort4*>(d + off) = outv;
}

// ---------------- fused QKV NT GEMM + RoPE epilogue, grid (32, 24) --------
// blockIdx.y: [0,8)=Q(+rope+scale), [8,16)=K(+rope), [16,24)=V(transposed).
__global__ void gemm_qkv(const u16* __restrict__ A, const u16* __restrict__ W0,
                         const u16* __restrict__ W1, const u16* __restrict__ W2,
                         const float* __restrict__ freqs,
                         u16* __restrict__ Qo, u16* __restrict__ Ko,
                         u16* __restrict__ Vo) {
  __shared__ u16 As[128 * 32];
  __shared__ u16 Bs[128 * 32];
  const int by = blockIdx.y;
  const int wsel = by >> 3;
  const int n0 = (by & 7) * 128;
  const int m0 = blockIdx.x * 128;
  const u16* Bm = (wsel == 0) ? W0 : (wsel == 1) ? W1 : W2;
  const int t = threadIdx.x;
  const int w = t >> 6;
  const int lane = t & 63;
  const int wm = w >> 1, wn = w & 1;
  const int c = lane & 15, g = lane >> 4;
  const int srow = t >> 2, skoff = (t & 3) * 8;

  f32x4 acc[4][4] = {};

  const u16* ag = A + (size_t)(m0 + srow) * Dc + skoff;
  const u16* bg = Bm + (size_t)(n0 + srow) * Dc + skoff;
  u16* al = &As[(w * 16) * 32];
  u16* bl = &Bs[(w * 16) * 32];

  for (int k0 = 0; k0 < Dc; k0 += 32) {
    gload_lds16(ag + k0, al);
    gload_lds16(ag + k0 + (size_t)64 * Dc, al + 64 * 32);
    gload_lds16(bg + k0, bl);
    gload_lds16(bg + k0 + (size_t)64 * Dc, bl + 64 * 32);
    __syncthreads();
    bf16x8 a[4], b[4];
#pragma unroll
    for (int f = 0; f < 4; ++f) {
      a[f] = *(const bf16x8*)&As[(wm * 64 + f * 16 + c) * 32 + g * 8];
      b[f] = *(const bf16x8*)&Bs[(wn * 64 + f * 16 + c) * 32 + g * 8];
    }
#pragma unroll
    for (int fm = 0; fm < 4; ++fm)
#pragma unroll
      for (int fn = 0; fn < 4; ++fn)
        acc[fm][fn] =
            __builtin_amdgcn_mfma_f32_16x16x32_bf16(a[fm], b[fn], acc[fm][fn], 0, 0, 0);
    __syncthreads();
  }

  u16* dst = (wsel == 0) ? Qo : (wsel == 1) ? Ko : Vo;
  const float qsc = (wsel == 0) ? 0.125f * 1.44269504f : 1.0f;  // HD^-0.5*log2e
  const int codd = c & 1;
#pragma unroll
  for (int fm = 0; fm < 4; ++fm)
#pragma unroll
    for (int fn = 0; fn < 4; ++fn)
#pragma unroll
      for (int r = 0; r < 4; ++r) {
        const int m = m0 + wm * 64 + fm * 16 + g * 4 + r;
        const int n = n0 + wn * 64 + fn * 16 + c;
        float v = acc[fm][fn][r];
        const int b = m >> 11, s = m & (Sc - 1);
        const int hh = n >> 6, d = n & 63;
        size_t idx;
        if (wsel < 2) {
          const float other = __shfl_xor(v, 1);
          const float2 f = reinterpret_cast<const float2*>(freqs)[s * ROTc + (d >> 1)];
          v = codd ? (v * f.x + other * f.y) : (v * f.x - other * f.y);
          v *= qsc;
          idx = (((size_t)(b * Hc + hh) * Sc) + s) * HDc + d;
        } else {
          idx = ((size_t)(b * Hc + hh) * HDc + d) * Sc + s;
        }
        dst[idx] = f2bf(v);
      }
}

// ---------------- final GEMM: out = ab @ wo^T, 64x128 tile, grid (64,8) ---
__global__ void gemm_out(const u16* __restrict__ A, const u16* __restrict__ Bm,
                         float* __restrict__ C) {
  __shared__ u16 As[64 * 32];
  __shared__ u16 Bs[128 * 32];
  const int m0 = blockIdx.x * 64;
  const int n0 = blockIdx.y * 128;
  const int t = threadIdx.x;
  const int w = t >> 6;
  const int lane = t & 63;
  const int wm = w >> 1, wn = w & 1;  // wave tile 32x64
  const int c = lane & 15, g = lane >> 4;
  const int srow = t >> 2, skoff = (t & 3) * 8;

  f32x4 acc[2][4] = {};

  const u16* ag = A + (size_t)(m0 + srow) * Dc + skoff;
  const u16* bg = Bm + (size_t)(n0 + srow) * Dc + skoff;
  u16* al = &As[(w * 16) * 32];
  u16* bl = &Bs[(w * 16) * 32];

  for (int k0 = 0; k0 < Dc; k0 += 32) {
    gload_lds16(ag + k0, al);
    gload_lds16(bg + k0, bl);
    gload_lds16(bg + k0 + (size_t)64 * Dc, bl + 64 * 32);
    __syncthreads();
    bf16x8 a[2], b[4];
#pragma unroll
    for (int f = 0; f < 2; ++f)
      a[f] = *(const bf16x8*)&As[(wm * 32 + f * 16 + c) * 32 + g * 8];
#pragma unroll
    for (int f = 0; f < 4; ++f)
      b[f] = *(const bf16x8*)&Bs[(wn * 64 + f * 16 + c) * 32 + g * 8];
#pragma unroll
    for (int fm = 0; fm < 2; ++fm)
#pragma unroll
      for (int fn = 0; fn < 4; ++fn)
        acc[fm][fn] =
            __builtin_amdgcn_mfma_f32_16x16x32_bf16(a[fm], b[fn], acc[fm][fn], 0, 0, 0);
    __syncthreads();
  }

#pragma unroll
  for (int fm = 0; fm < 2; ++fm)
#pragma unroll
    for (int fn = 0; fn < 4; ++fn)
#pragma unroll
      for (int r = 0; r < 4; ++r) {
        const int m = m0 + wm * 32 + fm * 16 + g * 4 + r;
        const int n = n0 + wn * 64 + fn * 16 + c;
        C[(size_t)m * Dc + n] = acc[fm][fn][r];
      }
}

// ---------------- flash attention: in-block split-KV, 8 waves -------------
// Q(BH,S,64) K(BH,S,64) Vt(BH,64,S).  512 thr = 2 groups x 4 waves.
// Group g covers kv [g*1024, g*1024+1024) for the SAME 128 q-rows; each
// group double-buffers its own K/V LDS (64KB total -> 2 blocks/CU ->
// 16 waves/CU = 4/SIMD, 2x round-11 TLP).  Final merge IN LDS (K/V space is
// dead after the loop): group 1 writes raw O(f32)+m+l, group 0 does the
// exact LSE combine + single global store.  No extra HBM traffic (round-8's
// global split-KV paid +30MB and lost).  Tile loop identical to round 11.
// v_permlane32_swap BANNED (failed r5+r10); all exchanges via __shfl_xor.
__global__ __launch_bounds__(512, 4) void flash_attn(
    const u16* __restrict__ Q, const u16* __restrict__ Kb,
    const u16* __restrict__ Vt, u16* __restrict__ Ob) {
  __shared__ u16 smem[32768];  // [K: 2grp x 2buf x 4096] [V: same] = 64KB
  const int orig = blockIdx.x;
  const int wg = (orig & 7) * 64 + (orig >> 3);  // bijective XCD chunking
  const int bh = wg >> 4;
  const int q0 = (wg & 15) * 128;
  const int t = threadIdx.x, w = t >> 6, lane = t & 63;
  const int grp = w >> 2, wl = w & 3;
  const int ts = t & 255;  // thread index within group
  const int l31 = lane & 31, hi = lane >> 5;
  const int sr = ts >> 4;
  const int su = (ts & 15) ^ (sr & 15);
  const int skv = sr + ((su >> 3) << 5);  // source kv (K) / d (V) row
  const int sd8 = (su & 7) * 8;           // source col offset (u16)
  const int rsw = (l31 & 15);             // read-side slot swizzle

  const u16* Qp = Q + (size_t)bh * Sc * HDc;
  const u16* Kp = Kb + (size_t)bh * Sc * HDc;
  const u16* Vp = Vt + (size_t)bh * HDc * Sc;
  u16* const Kg = smem + grp * 8192;           // this group's K (2 bufs)
  u16* const Vg = smem + 16384 + grp * 8192;   // this group's V (2 bufs)

  const int q = q0 + wl * 32 + l31;
  bf16x8 aq[4];
#pragma unroll
  for (int kd = 0; kd < 4; ++kd)
    aq[kd] = *(const bf16x8*)(Qp + (size_t)q * HDc + kd * 16 + hi * 8);

  float m_run = -1e30f, l_run = 0.f;
  f32x16 o0 = {}, o1 = {};
  bf16x8 va0[4], va1[4];

  auto STAGE = [&](int tile, int bb) {
    const int base = grp * 1024 + tile * 64;
    gload_lds16(Kp + (size_t)(base + skv) * HDc + sd8, Kg + bb * 4096 + wl * 512);
    gload_lds16(Kp + (size_t)(base + skv + 16) * HDc + sd8,
                Kg + bb * 4096 + 2048 + wl * 512);
    gload_lds16(Vp + (size_t)skv * Sc + base + sd8, Vg + bb * 4096 + wl * 512);
    gload_lds16(Vp + (size_t)(skv + 16) * Sc + base + sd8,
                Vg + bb * 4096 + 2048 + wl * 512);
  };
  auto QKF = [&](const u16* kbase, f32x16& S0, f32x16& S1) {
    __builtin_amdgcn_s_setprio(1);
#pragma unroll
    for (int kd = 0; kd < 4; ++kd) {
      const int u0 = kd * 2 + hi;
      bf16x8 a0 = *(const bf16x8*)&kbase[l31 * 128 + (u0 ^ rsw) * 8];
      bf16x8 a1 = *(const bf16x8*)&kbase[l31 * 128 + ((u0 + 8) ^ rsw) * 8];
      S0 = __builtin_amdgcn_mfma_f32_32x32x16_bf16(a0, aq[kd], S0, 0, 0, 0);
      S1 = __builtin_amdgcn_mfma_f32_32x32x16_bf16(a1, aq[kd], S1, 0, 0, 0);
    }
    __builtin_amdgcn_s_setprio(0);
  };
  auto LOADV = [&](const u16* vbase) {
#pragma unroll
    for (int ks = 0; ks < 4; ++ks) {
      const int uv = ks * 2 + hi;
      va0[ks] = *(const bf16x8*)&vbase[l31 * 128 + (uv ^ rsw) * 8];
      va1[ks] = *(const bf16x8*)&vbase[l31 * 128 + ((uv + 8) ^ rsw) * 8];
    }
  };
  auto SMPV = [&](f32x16& S0, f32x16& S1) {
    f32x2 t4[4];
#pragma unroll
    for (int i = 0; i < 4; ++i) {
      f32x2 e0; e0.x = S0[2 * i]; e0.y = S0[2 * i + 1];
      f32x2 e1; e1.x = S0[2 * i + 8]; e1.y = S0[2 * i + 9];
      f32x2 e2; e2.x = S1[2 * i]; e2.y = S1[2 * i + 1];
      f32x2 e3; e3.x = S1[2 * i + 8]; e3.y = S1[2 * i + 9];
      t4[i] = pmax2(pmax2(e0, e1), pmax2(e2, e3));
    }
    f32x2 tp = pmax2(pmax2(t4[0], t4[1]), pmax2(t4[2], t4[3]));
    float mt = fmaxf(tp.x, tp.y);
    mt = fmaxf(mt, __shfl_xor(mt, 32));
    const bool skip = __all(mt <= m_run + 8.0f);
    if (!skip) {
      const float mn2 = fmaxf(m_run, mt);
      const float scl = __builtin_amdgcn_exp2f(m_run - mn2);
      m_run = mn2;
      l_run *= scl;
      o0 *= scl;
      o1 *= scl;
    }
    const float mn = m_run;
#pragma unroll
    for (int r = 0; r < 16; ++r) {
      S0[r] = __builtin_amdgcn_exp2f(S0[r] - mn);
      S1[r] = __builtin_amdgcn_exp2f(S1[r] - mn);
    }
    f32x2 ac;
    ac.x = 0.f; ac.y = 0.f;
#pragma unroll
    for (int i = 0; i < 8; ++i) {
      f32x2 e0; e0.x = S0[2 * i]; e0.y = S0[2 * i + 1];
      f32x2 e1; e1.x = S1[2 * i]; e1.y = S1[2 * i + 1];
      ac += e0 + e1;
    }
    float rs = ac.x + ac.y;
    rs += __shfl_xor(rs, 32);
    l_run += rs;
    unsigned pk0[8], pk1[8];
#pragma unroll
    for (int B = 0; B < 4; ++B)
#pragma unroll
      for (int s2 = 0; s2 < 2; ++s2) {
        pk0[B * 2 + s2] = cvtpk(S0[4 * B + 2 * s2], S0[4 * B + 2 * s2 + 1]);
        pk1[B * 2 + s2] = cvtpk(S1[4 * B + 2 * s2], S1[4 * B + 2 * s2 + 1]);
      }
    bf16x8 bpv[4];
#pragma unroll
    for (int ks = 0; ks < 4; ++ks) {
      const unsigned* pk = (ks >> 1) ? pk1 : pk0;
      const int m2 = (ks & 1) * 4;
      const unsigned A0 = pk[m2 + 0], A1 = pk[m2 + 1];
      const unsigned B0 = pk[m2 + 2], B1 = pk[m2 + 3];
      const unsigned L0 = hi ? B0 : A0, L1 = hi ? B1 : A1;
      const unsigned R0 = hi ? A0 : B0, R1 = hi ? A1 : B1;
      const unsigned X0 = __shfl_xor(R0, 32), X1 = __shfl_xor(R1, 32);
      union { unsigned u[4]; bf16x8 v; } bp;
      bp.u[0] = hi ? X0 : L0;
      bp.u[1] = hi ? X1 : L1;
      bp.u[2] = hi ? L0 : X0;
      bp.u[3] = hi ? L1 : X1;
      bpv[ks] = bp.v;
    }
    __builtin_amdgcn_s_setprio(1);
#pragma unroll
    for (int ks = 0; ks < 4; ++ks) {
      o0 = __builtin_amdgcn_mfma_f32_32x32x16_bf16(va0[ks], bpv[ks], o0, 0, 0, 0);
      o1 = __builtin_amdgcn_mfma_f32_32x32x16_bf16(va1[ks], bpv[ks], o1, 0, 0, 0);
    }
    __builtin_amdgcn_s_setprio(0);
  };

  // prologue: stage this group's tiles 0,1; QK(0); V(0)->regs
  STAGE(0, 0);
  STAGE(1, 1);
  __syncthreads();
  f32x16 sp0 = {}, sp1 = {};
  QKF(Kg, sp0, sp1);
  LOADV(Vg);
  __syncthreads();

  int buf = 1;
  for (int tt = 1; tt < 16; ++tt) {
    if (tt < 15) STAGE(tt + 1, buf ^ 1);
    f32x16 sn0 = {}, sn1 = {};
    QKF(Kg + buf * 4096, sn0, sn1);
    SMPV(sp0, sp1);
    LOADV(Vg + buf * 4096);
    __syncthreads();
    sp0 = sn0;
    sp1 = sn1;
    buf ^= 1;
  }
  SMPV(sp0, sp1);  // last tile of this group's half

  // ---- in-LDS merge: group 1 -> LDS (raw O + m + l), group 0 combines ----
  float* fl = reinterpret_cast<float*>(smem);
  const int slot = (wl * 64 + lane) * 35;  // stride 35: conflict-free-ish
  __syncthreads();                         // all K/V reads done; safe to reuse
  if (grp == 1) {
#pragma unroll
    for (int j = 0; j < 16; ++j) fl[slot + j] = o0[j];
#pragma unroll
    for (int j = 0; j < 16; ++j) fl[slot + 16 + j] = o1[j];
    fl[slot + 32] = m_run;
    fl[slot + 33] = l_run;
  }
  __syncthreads();
  if (grp == 0) {
    const float mB = fl[slot + 32], lB = fl[slot + 33];
    const float mx = fmaxf(m_run, mB);
    const float sA = __builtin_amdgcn_exp2f(m_run - mx);
    const float sB = __builtin_amdgcn_exp2f(mB - mx);
    const float rd = 1.0f / (l_run * sA + lB * sB);
    const float cA = sA * rd, cB = sB * rd;
    const int b = bh >> 4, hh = bh & 15;
    u16* orow = Ob + ((size_t)b * Sc + q) * Dc + hh * HDc;
#pragma unroll
    for (int B2 = 0; B2 < 4; ++B2) {
      const float v0 = o0[4 * B2 + 0] * cA + fl[slot + 4 * B2 + 0] * cB;
      const float v1 = o0[4 * B2 + 1] * cA + fl[slot + 4 * B2 + 1] * cB;
      const float v2 = o0[4 * B2 + 2] * cA + fl[slot + 4 * B2 + 2] * cB;
      const float v3 = o0[4 * B2 + 3] * cA + fl[slot + 4 * B2 + 3] * cB;
      uint2 pv;
      pv.x = cvtpk(v0, v1);
      pv.y = cvtpk(v2, v3);
      *reinterpret_cast<uint2*>(orow + 8 * B2 + 4 * hi) = pv;
    }
#pragma unroll
    for (int B2 = 0; B2 < 4; ++B2) {
      const float v0 = o1[4 * B2 + 0] * cA + fl[slot + 16 + 4 * B2 + 0] * cB;
      const float v1 = o1[4 * B2 + 1] * cA + fl[slot + 16 + 4 * B2 + 1] * cB;
      const float v2 = o1[4 * B2 + 2] * cA + fl[slot + 16 + 4 * B2 + 2] * cB;
      const float v3 = o1[4 * B2 + 3] * cA + fl[slot + 16 + 4 * B2 + 3] * cB;
      uint2 pv;
      pv.x = cvtpk(v0, v1);
      pv.y = cvtpk(v2, v3);
      *reinterpret_cast<uint2*>(orow + 32 + 8 * B2 + 4 * hi) = pv;
    }
  }
}

extern "C" void kernel_launch(void* const* d_in, const int* in_sizes, int n_in,
                              void* d_out, int out_size, void* d_ws, size_t ws_size,
                              hipStream_t stream) {
  (void)in_sizes; (void)n_in; (void)out_size; (void)ws_size;
  const float* hidden = (const float*)d_in[0];
  const float* freqs = (const float*)d_in[1];
  const float* wq = (const float*)d_in[2];
  const float* wk = (const float*)d_in[3];
  const float* wv = (const float*)d_in[4];
  const float* wo = (const float*)d_in[5];
  float* out = (float*)d_out;

  char* ws = (char*)d_ws;
  const size_t MB8 = (size_t)Mrows * Dc * 2;  // 8 MiB
  const size_t WB = (size_t)Dc * Dc * 2;      // 2 MiB
  u16* hb = (u16*)ws;  ws += MB8;
  u16* wqb = (u16*)ws; ws += WB;
  u16* wkb = (u16*)ws; ws += WB;
  u16* wvb = (u16*)ws; ws += WB;
  u16* wob = (u16*)ws; ws += WB;
  u16* qb = (u16*)ws;  ws += MB8;
  u16* kb = (u16*)ws;  ws += MB8;
  u16* vtb = (u16*)ws; ws += MB8;
  u16* ab = (u16*)ws;  ws += MB8;

  cvt_all<<<8192, 256, 0, stream>>>(hidden, wq, wk, wv, wo, hb, wqb, wkb, wvb, wob);
  gemm_qkv<<<dim3(32, 24), 256, 0, stream>>>(hb, wqb, wkb, wvb, freqs, qb, kb, vtb);
  flash_attn<<<512, 512, 0, stream>>>(qb, kb, vtb, ab);
  gemm_out<<<dim3(64, 8), 256, 0, stream>>>(ab, wob, out);
}

// Round 13
// 127.863 us; speedup vs baseline: 2.5914x; 2.5914x over previous
//
#include <hip/hip_runtime.h>
#include <hip/hip_bf16.h>

typedef __attribute__((ext_vector_type(8))) short bf16x8;
typedef __attribute__((ext_vector_type(4))) float f32x4;
typedef __attribute__((ext_vector_type(16))) float f32x16;
typedef __attribute__((ext_vector_type(2))) float f32x2;
typedef unsigned short u16;

#define Bc   2
#define Sc   2048
#define Dc   1024
#define Hc   16
#define HDc  64
#define ROTc 32
#define Mrows 4096  // B*S

__device__ __forceinline__ u16 f2bf(float x) {
  union { float f; unsigned u; } v{x};
  unsigned r = v.u + 0x7fffu + ((v.u >> 16) & 1u);
  return (u16)(r >> 16);
}
__device__ __forceinline__ float bf2f(u16 x) {
  union { unsigned u; float f; } v{(unsigned)x << 16};
  return v.f;
}
__device__ __forceinline__ unsigned cvtpk(float a, float b) {
  unsigned r;
  asm("v_cvt_pk_bf16_f32 %0, %1, %2" : "=v"(r) : "v"(a), "v"(b));
  return r;
}
__device__ __forceinline__ f32x2 pmax2(f32x2 a, f32x2 b) {
  f32x2 r;
  r.x = fmaxf(a.x, b.x);
  r.y = fmaxf(a.y, b.y);
  return r;
}

__device__ __forceinline__ void gload_lds16(const void* g, void* l) {
  __builtin_amdgcn_global_load_lds(
      (const __attribute__((address_space(1))) void*)g,
      (__attribute__((address_space(3))) void*)l, 16, 0, 0);
}

// ---------------- f32 -> bf16 conversion (hidden + 4 weights in one grid) --
__global__ void cvt_all(const float* __restrict__ h, const float* __restrict__ q,
                        const float* __restrict__ k, const float* __restrict__ v,
                        const float* __restrict__ o,
                        u16* __restrict__ hb, u16* __restrict__ qb, u16* __restrict__ kb,
                        u16* __restrict__ vb, u16* __restrict__ ob) {
  size_t i = ((size_t)blockIdx.x * 256 + threadIdx.x) * 4;
  const float* s;
  u16* d;
  size_t off;
  if (i < (size_t)Mrows * Dc) {
    s = h; d = hb; off = i;
  } else {
    size_t j = i - (size_t)Mrows * Dc;
    int w = (int)(j >> 20);            // 1M elements per weight
    off = j & ((1u << 20) - 1);
    s = (w == 0) ? q : (w == 1) ? k : (w == 2) ? v : o;
    d = (w == 0) ? qb : (w == 1) ? kb : (w == 2) ? vb : ob;
  }
  float4 val = *reinterpret_cast<const float4*>(s + off);
  u16 r0 = f2bf(val.x), r1 = f2bf(val.y), r2 = f2bf(val.z), r3 = f2bf(val.w);
  ushort4 outv = {r0, r1, r2, r3};
  *reinterpret_cast<ushort4*>(d + off) = outv;
}

// ---------------- fused QKV NT GEMM + RoPE epilogue, grid (32, 24) --------
// blockIdx.y: [0,8)=Q(+rope+scale), [8,16)=K(+rope), [16,24)=V(transposed).
__global__ void gemm_qkv(const u16* __restrict__ A, const u16* __restrict__ W0,
                         const u16* __restrict__ W1, const u16* __restrict__ W2,
                         const float* __restrict__ freqs,
                         u16* __restrict__ Qo, u16* __restrict__ Ko,
                         u16* __restrict__ Vo) {
  __shared__ u16 As[128 * 32];
  __shared__ u16 Bs[128 * 32];
  const int by = blockIdx.y;
  const int wsel = by >> 3;
  const int n0 = (by & 7) * 128;
  const int m0 = blockIdx.x * 128;
  const u16* Bm = (wsel == 0) ? W0 : (wsel == 1) ? W1 : W2;
  const int t = threadIdx.x;
  const int w = t >> 6;
  const int lane = t & 63;
  const int wm = w >> 1, wn = w & 1;
  const int c = lane & 15, g = lane >> 4;
  const int srow = t >> 2, skoff = (t & 3) * 8;

  f32x4 acc[4][4] = {};

  const u16* ag = A + (size_t)(m0 + srow) * Dc + skoff;
  const u16* bg = Bm + (size_t)(n0 + srow) * Dc + skoff;
  u16* al = &As[(w * 16) * 32];
  u16* bl = &Bs[(w * 16) * 32];

  for (int k0 = 0; k0 < Dc; k0 += 32) {
    gload_lds16(ag + k0, al);
    gload_lds16(ag + k0 + (size_t)64 * Dc, al + 64 * 32);
    gload_lds16(bg + k0, bl);
    gload_lds16(bg + k0 + (size_t)64 * Dc, bl + 64 * 32);
    __syncthreads();
    bf16x8 a[4], b[4];
#pragma unroll
    for (int f = 0; f < 4; ++f) {
      a[f] = *(const bf16x8*)&As[(wm * 64 + f * 16 + c) * 32 + g * 8];
      b[f] = *(const bf16x8*)&Bs[(wn * 64 + f * 16 + c) * 32 + g * 8];
    }
#pragma unroll
    for (int fm = 0; fm < 4; ++fm)
#pragma unroll
      for (int fn = 0; fn < 4; ++fn)
        acc[fm][fn] =
            __builtin_amdgcn_mfma_f32_16x16x32_bf16(a[fm], b[fn], acc[fm][fn], 0, 0, 0);
    __syncthreads();
  }

  u16* dst = (wsel == 0) ? Qo : (wsel == 1) ? Ko : Vo;
  const float qsc = (wsel == 0) ? 0.125f * 1.44269504f : 1.0f;  // HD^-0.5*log2e
  const int codd = c & 1;
#pragma unroll
  for (int fm = 0; fm < 4; ++fm)
#pragma unroll
    for (int fn = 0; fn < 4; ++fn)
#pragma unroll
      for (int r = 0; r < 4; ++r) {
        const int m = m0 + wm * 64 + fm * 16 + g * 4 + r;
        const int n = n0 + wn * 64 + fn * 16 + c;
        float v = acc[fm][fn][r];
        const int b = m >> 11, s = m & (Sc - 1);
        const int hh = n >> 6, d = n & 63;
        size_t idx;
        if (wsel < 2) {
          const float other = __shfl_xor(v, 1);
          const float2 f = reinterpret_cast<const float2*>(freqs)[s * ROTc + (d >> 1)];
          v = codd ? (v * f.x + other * f.y) : (v * f.x - other * f.y);
          v *= qsc;
          idx = (((size_t)(b * Hc + hh) * Sc) + s) * HDc + d;
        } else {
          idx = ((size_t)(b * Hc + hh) * HDc + d) * Sc + s;
        }
        dst[idx] = f2bf(v);
      }
}

// ---------------- final GEMM: out = ab @ wo^T, 64x128 tile, grid (64,8) ---
__global__ void gemm_out(const u16* __restrict__ A, const u16* __restrict__ Bm,
                         float* __restrict__ C) {
  __shared__ u16 As[64 * 32];
  __shared__ u16 Bs[128 * 32];
  const int m0 = blockIdx.x * 64;
  const int n0 = blockIdx.y * 128;
  const int t = threadIdx.x;
  const int w = t >> 6;
  const int lane = t & 63;
  const int wm = w >> 1, wn = w & 1;  // wave tile 32x64
  const int c = lane & 15, g = lane >> 4;
  const int srow = t >> 2, skoff = (t & 3) * 8;

  f32x4 acc[2][4] = {};

  const u16* ag = A + (size_t)(m0 + srow) * Dc + skoff;
  const u16* bg = Bm + (size_t)(n0 + srow) * Dc + skoff;
  u16* al = &As[(w * 16) * 32];
  u16* bl = &Bs[(w * 16) * 32];

  for (int k0 = 0; k0 < Dc; k0 += 32) {
    gload_lds16(ag + k0, al);
    gload_lds16(bg + k0, bl);
    gload_lds16(bg + k0 + (size_t)64 * Dc, bl + 64 * 32);
    __syncthreads();
    bf16x8 a[2], b[4];
#pragma unroll
    for (int f = 0; f < 2; ++f)
      a[f] = *(const bf16x8*)&As[(wm * 32 + f * 16 + c) * 32 + g * 8];
#pragma unroll
    for (int f = 0; f < 4; ++f)
      b[f] = *(const bf16x8*)&Bs[(wn * 64 + f * 16 + c) * 32 + g * 8];
#pragma unroll
    for (int fm = 0; fm < 2; ++fm)
#pragma unroll
      for (int fn = 0; fn < 4; ++fn)
        acc[fm][fn] =
            __builtin_amdgcn_mfma_f32_16x16x32_bf16(a[fm], b[fn], acc[fm][fn], 0, 0, 0);
    __syncthreads();
  }

#pragma unroll
  for (int fm = 0; fm < 2; ++fm)
#pragma unroll
    for (int fn = 0; fn < 4; ++fn)
#pragma unroll
      for (int r = 0; r < 4; ++r) {
        const int m = m0 + wm * 32 + fm * 16 + g * 4 + r;
        const int n = n0 + wn * 64 + fn * 16 + c;
        C[(size_t)m * Dc + n] = acc[fm][fn][r];
      }
}

// ---------------- flash attention: in-block split-KV, register-thin -------
// 512 thr = 2 groups x 4 waves; group g covers kv [g*1024, (g+1)*1024) for
// the SAME 128 q-rows.  NON-pipelined round-7 body (76 VGPR proven; r11
// showed pipelining is neutral) so VGPR stays ~<=128 -> HW co-schedules
// 2 blocks/CU (64KB LDS) = 16 waves/CU, 2x r11 TLP, zero extra HBM traffic.
// In-LDS LSE merge (K/V space dead after loop).  launch_bounds(512,2) only
// (r12 lesson: (512,4) + fat kernel => VGPR capped 64, 485MB scratch spill).
// v_permlane32_swap BANNED (r5+r10); all exchanges via __shfl_xor.
__global__ __launch_bounds__(512, 2) void flash_attn(
    const u16* __restrict__ Q, const u16* __restrict__ Kb,
    const u16* __restrict__ Vt, u16* __restrict__ Ob) {
  __shared__ u16 smem[32768];  // K: grp*8192+buf*4096 ; V: +16384 (64 KB)
  const int orig = blockIdx.x;
  const int wg = (orig & 7) * 64 + (orig >> 3);  // bijective XCD chunking
  const int bh = wg >> 4;
  const int q0 = (wg & 15) * 128;
  const int t = threadIdx.x, w = t >> 6, lane = t & 63;
  const int grp = w >> 2, wl = w & 3;
  const int ts = t & 255;  // thread index within group
  const int l31 = lane & 31, hi = lane >> 5;
  const int sr = ts >> 4;
  const int su = (ts & 15) ^ (sr & 15);
  const int skv = sr + ((su >> 3) << 5);  // source kv (K) / d (V) row
  const int sd8 = (su & 7) * 8;           // source col offset (u16)
  const int rsw = (l31 & 15);             // read-side slot swizzle

  const u16* Qp = Q + (size_t)bh * Sc * HDc;
  const u16* Kp = Kb + (size_t)bh * Sc * HDc;
  const u16* Vp = Vt + (size_t)bh * HDc * Sc;
  u16* const Kg = smem + grp * 8192;
  u16* const Vg = smem + 16384 + grp * 8192;

  const int q = q0 + wl * 32 + l31;
  bf16x8 aq[4];
#pragma unroll
  for (int kd = 0; kd < 4; ++kd)
    aq[kd] = *(const bf16x8*)(Qp + (size_t)q * HDc + kd * 16 + hi * 8);

  float m_run = -1e30f, l_run = 0.f;
  f32x16 o0 = {}, o1 = {};

  auto STAGE = [&](int tile, int bb) {
    const int base = grp * 1024 + tile * 64;
    gload_lds16(Kp + (size_t)(base + skv) * HDc + sd8, Kg + bb * 4096 + wl * 512);
    gload_lds16(Kp + (size_t)(base + skv + 16) * HDc + sd8,
                Kg + bb * 4096 + 2048 + wl * 512);
    gload_lds16(Vp + (size_t)skv * Sc + base + sd8, Vg + bb * 4096 + wl * 512);
    gload_lds16(Vp + (size_t)(skv + 16) * Sc + base + sd8,
                Vg + bb * 4096 + 2048 + wl * 512);
  };

  // prologue: stage this group's tile 0 into buf 0
  STAGE(0, 0);
  __syncthreads();

  int buf = 0;
  for (int tt = 0; tt < 16; ++tt) {
    if (tt + 1 < 16) STAGE(tt + 1, buf ^ 1);
    const u16* kb2 = Kg + buf * 4096;
    const u16* vb2 = Vg + buf * 4096;
    // QK^T (swapped): s0 rows = kv l31 ; s1 rows = kv 32+l31 ; cols = q
    f32x16 s0 = {}, s1 = {};
    __builtin_amdgcn_s_setprio(1);
#pragma unroll
    for (int kd = 0; kd < 4; ++kd) {
      const int u0 = kd * 2 + hi;
      bf16x8 a0 = *(const bf16x8*)&kb2[l31 * 128 + (u0 ^ rsw) * 8];
      bf16x8 a1 = *(const bf16x8*)&kb2[l31 * 128 + ((u0 + 8) ^ rsw) * 8];
      s0 = __builtin_amdgcn_mfma_f32_32x32x16_bf16(a0, aq[kd], s0, 0, 0, 0);
      s1 = __builtin_amdgcn_mfma_f32_32x32x16_bf16(a1, aq[kd], s1, 0, 0, 0);
    }
    __builtin_amdgcn_s_setprio(0);
    // packed-f32 row max (lane-local + one cross-half shuffle)
    f32x2 t4[4];
#pragma unroll
    for (int i = 0; i < 4; ++i) {
      f32x2 e0; e0.x = s0[2 * i]; e0.y = s0[2 * i + 1];
      f32x2 e1; e1.x = s0[2 * i + 8]; e1.y = s0[2 * i + 9];
      f32x2 e2; e2.x = s1[2 * i]; e2.y = s1[2 * i + 1];
      f32x2 e3; e3.x = s1[2 * i + 8]; e3.y = s1[2 * i + 9];
      t4[i] = pmax2(pmax2(e0, e1), pmax2(e2, e3));
    }
    f32x2 tp = pmax2(pmax2(t4[0], t4[1]), pmax2(t4[2], t4[3]));
    float mt = fmaxf(tp.x, tp.y);
    mt = fmaxf(mt, __shfl_xor(mt, 32));
    const bool skip = __all(mt <= m_run + 8.0f);
    if (!skip) {
      const float mn2 = fmaxf(m_run, mt);
      const float scl = __builtin_amdgcn_exp2f(m_run - mn2);
      m_run = mn2;
      l_run *= scl;
      o0 *= scl;
      o1 *= scl;
    }
    const float mn = m_run;
#pragma unroll
    for (int r = 0; r < 16; ++r) {
      s0[r] = __builtin_amdgcn_exp2f(s0[r] - mn);
      s1[r] = __builtin_amdgcn_exp2f(s1[r] - mn);
    }
    f32x2 ac;
    ac.x = 0.f; ac.y = 0.f;
#pragma unroll
    for (int i = 0; i < 8; ++i) {
      f32x2 e0; e0.x = s0[2 * i]; e0.y = s0[2 * i + 1];
      f32x2 e1; e1.x = s1[2 * i]; e1.y = s1[2 * i + 1];
      ac += e0 + e1;
    }
    float rs = ac.x + ac.y;
    rs += __shfl_xor(rs, 32);
    l_run += rs;
    // pack P to bf16 pairs: pk[kb][2B+s] covers kv = kb*32+8B+4*hi+2s(+1)
    unsigned pk0[8], pk1[8];
#pragma unroll
    for (int B = 0; B < 4; ++B)
#pragma unroll
      for (int s2 = 0; s2 < 2; ++s2) {
        pk0[B * 2 + s2] = cvtpk(s0[4 * B + 2 * s2], s0[4 * B + 2 * s2 + 1]);
        pk1[B * 2 + s2] = cvtpk(s1[4 * B + 2 * s2], s1[4 * B + 2 * s2 + 1]);
      }
    // PV: O = mfma(A=V^T, B=P); V fragments read inline from LDS
#pragma unroll
    for (int ks = 0; ks < 4; ++ks) {
      const unsigned* pk = (ks >> 1) ? pk1 : pk0;
      const int m2 = (ks & 1) * 4;
      const unsigned A0 = pk[m2 + 0], A1 = pk[m2 + 1];
      const unsigned B0 = pk[m2 + 2], B1 = pk[m2 + 3];
      const unsigned L0 = hi ? B0 : A0, L1 = hi ? B1 : A1;
      const unsigned R0 = hi ? A0 : B0, R1 = hi ? A1 : B1;
      const unsigned X0 = __shfl_xor(R0, 32), X1 = __shfl_xor(R1, 32);
      union { unsigned u[4]; bf16x8 v; } bp;
      bp.u[0] = hi ? X0 : L0;
      bp.u[1] = hi ? X1 : L1;
      bp.u[2] = hi ? L0 : X0;
      bp.u[3] = hi ? L1 : X1;
      const int uv = ks * 2 + hi;
      bf16x8 va0 = *(const bf16x8*)&vb2[l31 * 128 + (uv ^ rsw) * 8];
      bf16x8 va1 = *(const bf16x8*)&vb2[l31 * 128 + ((uv + 8) ^ rsw) * 8];
      __builtin_amdgcn_s_setprio(1);
      o0 = __builtin_amdgcn_mfma_f32_32x32x16_bf16(va0, bp.v, o0, 0, 0, 0);
      o1 = __builtin_amdgcn_mfma_f32_32x32x16_bf16(va1, bp.v, o1, 0, 0, 0);
      __builtin_amdgcn_s_setprio(0);
    }
    __syncthreads();  // stage t+1 landed; all reads of buf done
    buf ^= 1;
  }

  // ---- in-LDS merge: group 1 -> LDS (raw O + m + l), group 0 combines ----
  // slot stride 35 floats (odd) -> lanes hit distinct banks.
  float* fl = reinterpret_cast<float*>(smem);
  const int slot = (wl * 64 + lane) * 35;
  if (grp == 1) {
#pragma unroll
    for (int j = 0; j < 16; ++j) fl[slot + j] = o0[j];
#pragma unroll
    for (int j = 0; j < 16; ++j) fl[slot + 16 + j] = o1[j];
    fl[slot + 32] = m_run;
    fl[slot + 33] = l_run;
  }
  __syncthreads();
  if (grp == 0) {
    const float mB = fl[slot + 32], lB = fl[slot + 33];
    const float mx = fmaxf(m_run, mB);
    const float sA = __builtin_amdgcn_exp2f(m_run - mx);
    const float sB = __builtin_amdgcn_exp2f(mB - mx);
    const float rd = 1.0f / (l_run * sA + lB * sB);
    const float cA = sA * rd, cB = sB * rd;
    const int b = bh >> 4, hh = bh & 15;
    u16* orow = Ob + ((size_t)b * Sc + q) * Dc + hh * HDc;
#pragma unroll
    for (int B2 = 0; B2 < 4; ++B2) {
      const float v0 = o0[4 * B2 + 0] * cA + fl[slot + 4 * B2 + 0] * cB;
      const float v1 = o0[4 * B2 + 1] * cA + fl[slot + 4 * B2 + 1] * cB;
      const float v2 = o0[4 * B2 + 2] * cA + fl[slot + 4 * B2 + 2] * cB;
      const float v3 = o0[4 * B2 + 3] * cA + fl[slot + 4 * B2 + 3] * cB;
      uint2 pv;
      pv.x = cvtpk(v0, v1);
      pv.y = cvtpk(v2, v3);
      *reinterpret_cast<uint2*>(orow + 8 * B2 + 4 * hi) = pv;
    }
#pragma unroll
    for (int B2 = 0; B2 < 4; ++B2) {
      const float v0 = o1[4 * B2 + 0] * cA + fl[slot + 16 + 4 * B2 + 0] * cB;
      const float v1 = o1[4 * B2 + 1] * cA + fl[slot + 16 + 4 * B2 + 1] * cB;
      const float v2 = o1[4 * B2 + 2] * cA + fl[slot + 16 + 4 * B2 + 2] * cB;
      const float v3 = o1[4 * B2 + 3] * cA + fl[slot + 16 + 4 * B2 + 3] * cB;
      uint2 pv;
      pv.x = cvtpk(v0, v1);
      pv.y = cvtpk(v2, v3);
      *reinterpret_cast<uint2*>(orow + 32 + 8 * B2 + 4 * hi) = pv;
    }
  }
}

extern "C" void kernel_launch(void* const* d_in, const int* in_sizes, int n_in,
                              void* d_out, int out_size, void* d_ws, size_t ws_size,
                              hipStream_t stream) {
  (void)in_sizes; (void)n_in; (void)out_size; (void)ws_size;
  const float* hidden = (const float*)d_in[0];
  const float* freqs = (const float*)d_in[1];
  const float* wq = (const float*)d_in[2];
  const float* wk = (const float*)d_in[3];
  const float* wv = (const float*)d_in[4];
  const float* wo = (const float*)d_in[5];
  float* out = (float*)d_out;

  char* ws = (char*)d_ws;
  const size_t MB8 = (size_t)Mrows * Dc * 2;  // 8 MiB
  const size_t WB = (size_t)Dc * Dc * 2;      // 2 MiB
  u16* hb = (u16*)ws;  ws += MB8;
  u16* wqb = (u16*)ws; ws += WB;
  u16* wkb = (u16*)ws; ws += WB;
  u16* wvb = (u16*)ws; ws += WB;
  u16* wob = (u16*)ws; ws += WB;
  u16* qb = (u16*)ws;  ws += MB8;
  u16* kb = (u16*)ws;  ws += MB8;
  u16* vtb = (u16*)ws; ws += MB8;
  u16* ab = (u16*)ws;  ws += MB8;

  cvt_all<<<8192, 256, 0, stream>>>(hidden, wq, wk, wv, wo, hb, wqb, wkb, wvb, wob);
  gemm_qkv<<<dim3(32, 24), 256, 0, stream>>>(hb, wqb, wkb, wvb, freqs, qb, kb, vtb);
  flash_attn<<<512, 512, 0, stream>>>(qb, kb, vtb, ab);
  gemm_out<<<dim3(64, 8), 256, 0, stream>>>(ab, wob, out);
}